// Round 6
// baseline (176.182 us; speedup 1.0000x reference)
//
#include <hip/hip_runtime.h>

// Zero-phase bandpass FIR = one 8191-tap correlation with the kernel
// autocorrelation g, as an implicit-Toeplitz MFMA GEMM.
//   out[t] = sum_s g[s] * xe[t + s],  g = autocorr(k) (bf16, hi only)
// Round 6: occupancy. R=4 rows/block -> 32 KB LDS, 1024 blocks, 3 waves/SIMD
// (was 2 blocks/CU, 2/SIMD, 32% MfmaUtil = latency-stall bound). Async
// global_load_lds B-staging kept (round 5). Symmetric autocorr (half work).

#define T_LEN   131072
#define XE_LEN  139776
#define XE_U4   (XE_LEN / 8)      // 17472 uint4 per row
#define NCHUNK  312               // A chunks: table P in [0,312), p = P-24
#define QSTEPS  288               // 4 quarters x 72
#define QQ      72                // Q-steps per wave
#define SCH     8                 // Q-steps per LDS chunk
#define NCH     9                 // chunks per wave
#define ROWS    4                 // signal rows per block

typedef float  f32x4  __attribute__((ext_vector_type(4)));
typedef __bf16 bf16x8 __attribute__((ext_vector_type(8)));

// ---------- ws layout (bytes) ----------
#define WS_KZ   0                 // 12288 floats (zero-padded k)
#define WS_G    49152             // 8192 floats  (autocorrelation)
#define WS_AHI  81920             // 312*512 bf16 Toeplitz frags = 319488 B
#define WS_XE   401408            // 32*139776 bf16 padded signal
#define WS_END  9347072

__device__ __forceinline__ void gload_lds16(const uint4* g, uint4* lds) {
  __builtin_amdgcn_global_load_lds(
      (const __attribute__((address_space(1))) unsigned int*)g,
      (__attribute__((address_space(3))) unsigned int*)lds, 16, 0, 0);
}

// K0: kz[m] = zero-padded k; also zero g
__global__ void k_build_kz(const float* __restrict__ k, float* __restrict__ kz,
                           float* __restrict__ g) {
  int m = blockIdx.x * 256 + threadIdx.x;
  if (m < 12288) {
    int i = m - 4096;
    kz[m] = (i >= 0 && i < 4096) ? k[i] : 0.0f;
  }
  if (m < 8192) g[m] = 0.0f;
}

// K1: symmetric autocorr. s in [0,4096); mirror into g[8190-s] (g[s]=g[8190-s]).
// grid (16, 32): 4096 s-values x 32 i-chunks of 128.
__global__ void k_autocorr(const float* __restrict__ k,
                           const float* __restrict__ kz,
                           float* __restrict__ g) {
  int s = blockIdx.x * 256 + threadIdx.x;
  int i0 = blockIdx.y * 128;
  const float* kk  = k + i0;
  const float* kzs = kz + (8191 - s) + i0;   // 4-B aligned only
  float a0 = 0.f, a1 = 0.f, a2 = 0.f, a3 = 0.f;
  #pragma unroll 4
  for (int i = 0; i < 128; i += 4) {
    float4 kv = *(const float4*)(kk + i);
    float4 zv;
    __builtin_memcpy(&zv, kzs + i, 16);
    a0 = fmaf(kv.x, zv.x, a0);
    a1 = fmaf(kv.y, zv.y, a1);
    a2 = fmaf(kv.z, zv.z, a2);
    a3 = fmaf(kv.w, zv.w, a3);
  }
  float part = (a0 + a1) + (a2 + a3);
  atomicAdd(&g[s], part);
  if (s != 4095) atomicAdd(&g[8190 - s], part);
}

// K2: Toeplitz A fragments, fragment-ordered (chunk P, lane l, 8 bf16).
// A_p[i][k] = gpad[32p + k - i], lane l: i = l&15, k = (l>>4)*8 + jj.
__global__ void k_build_afrag(const float* __restrict__ g,
                              __bf16* __restrict__ Ahi) {
  int P = blockIdx.x;
  int t = threadIdx.x;
  int l = t >> 2;
  int jj0 = (t & 3) * 2;
  int q = l >> 4, i = l & 15;
  int p = P - 24;
  #pragma unroll
  for (int u = 0; u < 2; ++u) {
    int jj = jj0 + u;
    int s = 32 * p + 8 * q + jj - i;
    float val = (s >= 0 && s <= 8190) ? g[s] : 0.0f;
    Ahi[P * 512 + l * 8 + jj] = (__bf16)val;
  }
}

// K3: xe[row][w] = bf16( X(w-4095) ), reflect in [-2048, T+2048), else 0.
__global__ void k_build_xe(const float* __restrict__ x, __bf16* __restrict__ xe) {
  int e0 = (blockIdx.x * 256 + threadIdx.x) * 8;
  int row = blockIdx.y;
  if (e0 >= XE_LEN) return;
  const float* xr = x + (size_t)row * T_LEN;
  int v0 = e0 - 4095;
  bf16x8 outv;
  if (v0 >= 0 && v0 <= T_LEN - 8) {
    float4 f0, f1;
    __builtin_memcpy(&f0, xr + v0, 16);
    __builtin_memcpy(&f1, xr + v0 + 4, 16);
    outv[0] = (__bf16)f0.x; outv[1] = (__bf16)f0.y;
    outv[2] = (__bf16)f0.z; outv[3] = (__bf16)f0.w;
    outv[4] = (__bf16)f1.x; outv[5] = (__bf16)f1.y;
    outv[6] = (__bf16)f1.z; outv[7] = (__bf16)f1.w;
  } else {
    #pragma unroll
    for (int u = 0; u < 8; ++u) {
      int v = v0 + u;
      float val = 0.0f;
      if (v >= -2048 && v < T_LEN + 2048) {
        int v2 = v < 0 ? -v : v;
        v2 = v2 >= T_LEN ? 2 * T_LEN - 2 - v2 : v2;
        val = xr[v2];
      }
      outv[u] = (__bf16)val;
    }
  }
  ((uint4*)(xe + (size_t)row * XE_LEN))[e0 >> 3] =
      __builtin_bit_cast(uint4, outv);
}

// Main: 256 threads = 4 waves; wave w computes Q-quarter w (72 Q-steps) of
// one 4-row x 1024-t tile. Per Q: 4 A global loads (L2), 4 ds_read_b128,
// 16 MFMAs. B staged chunk-wise (SCH=8 Qs) by async global_load_lds into a
// wave-private double buffer; manual vmcnt drain, no __syncthreads in loop.
// Grid (128, 8) = 1024 blocks, 32 KB LDS -> 3 blocks/CU (reg-limited at
// launch_bounds(256,3)), 12 waves/CU = 3/SIMD.
__global__ __launch_bounds__(256, 3) void k_fir_mfma(
    const uint4* __restrict__ xeu, const uint4* __restrict__ Ahi,
    float* __restrict__ out) {
  __shared__ uint4 sbB[2048];      // 32 KB: wave*512 + buf*256 + row*64

  const int tid = threadIdx.x;
  const int w   = tid >> 6;                  // wave = Q-quarter
  const int l   = tid & 63;
  const int q   = l >> 4;
  const int n   = l & 15;
  const int t0  = blockIdx.x << 10;          // 1024 outputs per block
  const int rbase = blockIdx.y << 2;         // 4 rows per block
  const int Qbeg  = w * QQ;
  const int lofs  = q + 2 * n;               // uint4 offset in B window

  // per-lane global base for staging (lane l covers uint4 slot l of a row)
  const uint4* gbase = xeu + (size_t)rbase * XE_U4 + (t0 >> 3) + 4 * Qbeg + l;
  uint4* sw = sbB + (w << 9);

  f32x4 acc[ROWS][4];
  #pragma unroll
  for (int r = 0; r < ROWS; ++r)
    #pragma unroll
    for (int m = 0; m < 4; ++m) acc[r][m] = (f32x4){0.f, 0.f, 0.f, 0.f};

  // stage chunk 0 into buf 0
  #pragma unroll
  for (int r = 0; r < ROWS; ++r)
    gload_lds16(gbase + (size_t)r * XE_U4, sw + (r << 6));
  asm volatile("s_waitcnt vmcnt(0)" ::: "memory");

  int buf = 0;
  for (int ch = 0; ch < NCH; ++ch) {         // NOT unrolled (I-cache)
    if (ch + 1 < NCH) {                      // async-stage next chunk
      uint4* dst = sw + ((buf ^ 1) << 8);
      const uint4* src = gbase + ((ch + 1) << 5);
      #pragma unroll
      for (int r = 0; r < ROWS; ++r)
        gload_lds16(src + (size_t)r * XE_U4, dst + (r << 6));
    }

    const uint4* bw = sw + (buf << 8) + lofs;
    #pragma unroll 2
    for (int Qr = 0; Qr < SCH; ++Qr) {
      const int Q = Qbeg + (ch << 3) + Qr;
      bf16x8 A[4];
      #pragma unroll
      for (int mt = 0; mt < 4; ++mt)
        A[mt] = __builtin_bit_cast(bf16x8, Ahi[(Q + 24 - 8 * mt) * 64 + l]);
      #pragma unroll
      for (int r = 0; r < ROWS; ++r) {
        bf16x8 B = __builtin_bit_cast(bf16x8, bw[(r << 6) + 4 * Qr]);
        #pragma unroll
        for (int mt = 0; mt < 4; ++mt)
          acc[r][mt] =
              __builtin_amdgcn_mfma_f32_16x16x32_bf16(A[mt], B, acc[r][mt], 0, 0, 0);
      }
    }

    if (ch + 1 < NCH) {
      asm volatile("s_waitcnt vmcnt(0)" ::: "memory");   // next buf ready
      buf ^= 1;
    }
  }

  // ---- combine 4 Q-quarter partials in LDS (phased, disjoint mt slices) ----
  __syncthreads();
  float* C = (float*)sbB;                    // 4 rows x 1024 t (16 KB)
  const int co = (q << 2) + (n << 4);        // C/D: col=n, row=(q*4+reg)
  #pragma unroll
  for (int ph = 0; ph < 4; ++ph) {
    const int mt = (w + ph) & 3;
    float* cp = C + (mt << 8) + co;
    if (ph == 0) {
      #pragma unroll
      for (int r = 0; r < ROWS; ++r)
        *(f32x4*)(cp + (r << 10)) = acc[r][mt];
    } else {
      #pragma unroll
      for (int r = 0; r < ROWS; ++r) {
        f32x4 v = *(f32x4*)(cp + (r << 10));
        v += acc[r][mt];
        *(f32x4*)(cp + (r << 10)) = v;
      }
    }
    __syncthreads();
  }

  // ---- coalesced store: 1024 f32x4, 256 threads x 4 ----
  #pragma unroll
  for (int u = 0; u < ROWS; ++u) {
    f32x4 v = ((f32x4*)C)[tid + (u << 8)];
    *(f32x4*)(out + (size_t)(rbase + u) * T_LEN + t0 + (tid << 2)) = v;
  }
}

extern "C" void kernel_launch(void* const* d_in, const int* in_sizes, int n_in,
                              void* d_out, int out_size, void* d_ws, size_t ws_size,
                              hipStream_t stream) {
  const float* x = (const float*)d_in[0];
  const float* k = (const float*)d_in[1];
  float* out = (float*)d_out;
  char* ws = (char*)d_ws;
  if (ws_size < (size_t)WS_END) return;

  float*  kz  = (float*)(ws + WS_KZ);
  float*  g   = (float*)(ws + WS_G);
  __bf16* Ahi = (__bf16*)(ws + WS_AHI);
  __bf16* xe  = (__bf16*)(ws + WS_XE);

  k_build_kz<<<dim3(48), dim3(256), 0, stream>>>(k, kz, g);
  k_autocorr<<<dim3(16, 32), dim3(256), 0, stream>>>(k, kz, g);
  k_build_afrag<<<dim3(NCHUNK), dim3(256), 0, stream>>>(g, Ahi);
  k_build_xe<<<dim3((XE_LEN / 8 + 255) / 256, 32), dim3(256), 0, stream>>>(x, xe);
  k_fir_mfma<<<dim3(T_LEN / 1024, 8), dim3(256), 0, stream>>>(
      (const uint4*)xe, (const uint4*)Ahi, out);
}